// Round 1
// baseline (522.947 us; speedup 1.0000x reference)
//
#include <hip/hip_runtime.h>
#include <float.h>

// MimiEuclideanCodebook: argmin_k ||x_n - e_k||^2 then gather e_k.
// x: [N=32768, D=256] fp32, embed_sum: [K=2048, D=256] fp32, usage: [K] fp32.
// e_k = embed_sum_k / max(usage_k, 1e-5). argmin_k(dist) == argmin_k(e_sq_k - 2*x.e_k)
// (x_sq is constant per n -> dropped; argmin-invariant).
//
// Outputs (flat float d_out): quantize [N*D] floats, then embed_ind [N] as floats.

#define EPSILON 1e-5f

constexpr int D     = 256;
constexpr int K_TOT = 2048;
constexpr int TN    = 128;   // n-tile per block
constexpr int TK    = 128;   // k-tile per iteration
constexpr int DC    = 32;    // d-chunk staged in LDS
constexpr int KS    = 2;     // k-split across blocks (occupancy: 512 blocks = 2/CU)
// LDS tiles stored transposed: [DC][TN] with +4-float pad per 8 cols.
// col c -> c + (c>>3)*4, so the 8-col fragments threads read stay float4-contiguous
// while stride-8 column access maps to bank stride 12 (2-way max = free).
// Row stride 196 (not 192) so it's not 0 mod 32 -> staging writes spread banks.
constexpr int RS    = 196;

__global__ void esq_kernel(const float* __restrict__ es,
                           const float* __restrict__ usage,
                           float* __restrict__ esq) {
  const int lane = threadIdx.x & 63;
  const int w    = threadIdx.x >> 6;
  const int k    = blockIdx.x * 4 + w;
  const float u  = fmaxf(usage[k], EPSILON);
  const float4 e = *(const float4*)(es + (size_t)k * D + lane * 4);
  // exact division to match reference's embed = embed_sum / clamp(usage)
  const float a = e.x / u, b = e.y / u, c = e.z / u, d = e.w / u;
  float s = a * a + b * b + c * c + d * d;
  #pragma unroll
  for (int m = 1; m < 64; m <<= 1) s += __shfl_xor(s, m, 64);
  if (lane == 0) esq[k] = s;
}

__global__ __launch_bounds__(256, 2)
void dist_kernel(const float* __restrict__ x,
                 const float* __restrict__ es,
                 const float* __restrict__ usage,
                 const float* __restrict__ esq,
                 float* __restrict__ bestd,
                 int* __restrict__ besti,
                 int N) {
  __shared__ float smX[DC * RS];
  __shared__ float smE[DC * RS];

  const int t    = threadIdx.x;
  const int tx   = t & 15;        // k-direction (8 cols each)
  const int ty   = t >> 4;        // n-direction (8 rows each)
  const int n0   = blockIdx.x * TN;
  const int half = blockIdx.y;

  float best[8];
  int   bidx[8];
  #pragma unroll
  for (int i = 0; i < 8; ++i) { best[i] = FLT_MAX; bidx[i] = 0; }

  for (int kt = 0; kt < (K_TOT / KS) / TK; ++kt) {
    const int k0 = half * (K_TOT / KS) + kt * TK;

    float acc[8][8];
    #pragma unroll
    for (int i = 0; i < 8; ++i)
      #pragma unroll
      for (int j = 0; j < 8; ++j) acc[i][j] = 0.f;

    for (int dc = 0; dc < D; dc += DC) {
      __syncthreads();
      // Stage x[TN x DC] and e[TK x DC] transposed into LDS.
      // f = i*256 + t: 64 lanes cover 8 rows x full 32 floats -> coalesced 128B/row.
      #pragma unroll
      for (int i = 0; i < 4; ++i) {
        const int f    = i * 256 + t;
        const int row  = f >> 3;
        const int c4   = f & 7;
        const int pcol = row + ((row >> 3) << 2);
        const float4 xv =
            *(const float4*)(x + (size_t)(n0 + row) * D + dc + c4 * 4);
        smX[(c4 * 4 + 0) * RS + pcol] = xv.x;
        smX[(c4 * 4 + 1) * RS + pcol] = xv.y;
        smX[(c4 * 4 + 2) * RS + pcol] = xv.z;
        smX[(c4 * 4 + 3) * RS + pcol] = xv.w;
        const int kk = k0 + row;
        const float rs = 1.0f / fmaxf(usage[kk], EPSILON);
        const float4 ev =
            *(const float4*)(es + (size_t)kk * D + dc + c4 * 4);
        smE[(c4 * 4 + 0) * RS + pcol] = ev.x * rs;
        smE[(c4 * 4 + 1) * RS + pcol] = ev.y * rs;
        smE[(c4 * 4 + 2) * RS + pcol] = ev.z * rs;
        smE[(c4 * 4 + 3) * RS + pcol] = ev.w * rs;
      }
      __syncthreads();

      #pragma unroll 4
      for (int d = 0; d < DC; ++d) {
        const float* px = &smX[d * RS + ty * 12];
        const float* pe = &smE[d * RS + tx * 12];
        const float4 xa = *(const float4*)px;
        const float4 xb = *(const float4*)(px + 4);
        const float4 ea = *(const float4*)pe;
        const float4 eb = *(const float4*)(pe + 4);
        const float xr[8] = {xa.x, xa.y, xa.z, xa.w, xb.x, xb.y, xb.z, xb.w};
        const float er[8] = {ea.x, ea.y, ea.z, ea.w, eb.x, eb.y, eb.z, eb.w};
        #pragma unroll
        for (int i = 0; i < 8; ++i)
          #pragma unroll
          for (int j = 0; j < 8; ++j)
            acc[i][j] = fmaf(xr[i], er[j], acc[i][j]);
      }
    }

    // dist = e_sq - 2*dot; ascending k with strict '<' == first-index tie-break.
    #pragma unroll
    for (int j = 0; j < 8; ++j) {
      const int k = k0 + tx * 8 + j;
      const float eq = esq[k];
      #pragma unroll
      for (int i = 0; i < 8; ++i) {
        const float dst = fmaf(-2.0f, acc[i][j], eq);
        if (dst < best[i]) { best[i] = dst; bidx[i] = k; }
      }
    }
  }

  // Reduce across tx (16 threads own disjoint ascending k-ranges per row).
  __syncthreads();
  float* rd = smX;            // 16*128 floats
  int*   ri = (int*)smE;      // 16*128 ints
  #pragma unroll
  for (int i = 0; i < 8; ++i) {
    const int r = ty * 8 + i;
    rd[tx * TN + r] = best[i];
    ri[tx * TN + r] = bidx[i];
  }
  __syncthreads();
  for (int off = 8; off >= 1; off >>= 1) {
    if (tx < off) {
      #pragma unroll
      for (int i = 0; i < 8; ++i) {
        const int r = ty * 8 + i;
        const float d1 = rd[tx * TN + r], d2 = rd[(tx + off) * TN + r];
        const int   i1 = ri[tx * TN + r], i2 = ri[(tx + off) * TN + r];
        if (d2 < d1 || (d2 == d1 && i2 < i1)) {
          rd[tx * TN + r] = d2;
          ri[tx * TN + r] = i2;
        }
      }
    }
    __syncthreads();
  }
  if (tx == 0) {
    #pragma unroll
    for (int i = 0; i < 8; ++i) {
      const int r = ty * 8 + i;
      bestd[(size_t)half * N + n0 + r] = rd[r];
      besti[(size_t)half * N + n0 + r] = ri[r];
    }
  }
}

__global__ void gather_kernel(const float* __restrict__ es,
                              const float* __restrict__ usage,
                              const float* __restrict__ bestd,
                              const int* __restrict__ besti,
                              float* __restrict__ out_q,
                              float* __restrict__ out_i,
                              int N) {
  const int w    = threadIdx.x >> 6;
  const int lane = threadIdx.x & 63;
  const int n    = blockIdx.x * 4 + w;
  const float d0 = bestd[n];
  const float d1 = bestd[(size_t)N + n];
  const int   i0 = besti[n];
  const int   i1 = besti[(size_t)N + n];
  // half-0 indices are always lower -> ties go to i0 (first-index semantics)
  const int idx = (d1 < d0) ? i1 : i0;
  const float u = fmaxf(usage[idx], EPSILON);
  const float4 e = *(const float4*)(es + (size_t)idx * D + lane * 4);
  float4 q;
  q.x = e.x / u; q.y = e.y / u; q.z = e.z / u; q.w = e.w / u;  // exact div
  *(float4*)(out_q + (size_t)n * D + lane * 4) = q;
  if (lane == 0) out_i[n] = (float)idx;
}

extern "C" void kernel_launch(void* const* d_in, const int* in_sizes, int n_in,
                              void* d_out, int out_size, void* d_ws, size_t ws_size,
                              hipStream_t stream) {
  const float* x     = (const float*)d_in[0];  // [N, 256]
  const float* es    = (const float*)d_in[1];  // [2048, 256]
  const float* usage = (const float*)d_in[2];  // [2048]
  const int N = in_sizes[0] / D;               // 32768

  float* ws    = (float*)d_ws;
  float* esq   = ws;                                   // K_TOT floats
  float* bestd = ws + K_TOT;                           // KS*N floats
  int*   besti = (int*)(ws + K_TOT + (size_t)KS * N);  // KS*N ints

  float* out_q = (float*)d_out;                 // N*D floats
  float* out_i = out_q + (size_t)N * D;         // N floats (indices as float)

  esq_kernel<<<K_TOT / 4, 256, 0, stream>>>(es, usage, esq);
  dist_kernel<<<dim3(N / TN, KS), 256, 0, stream>>>(x, es, usage, esq,
                                                    bestd, besti, N);
  gather_kernel<<<N / 4, 256, 0, stream>>>(es, usage, bestd, besti,
                                           out_q, out_i, N);
}

// Round 2
// 401.069 us; speedup vs baseline: 1.3039x; 1.3039x over previous
//
#include <hip/hip_runtime.h>
#include <float.h>
#include <stdint.h>

// MimiEuclideanCodebook: argmin_k ||x_n - e_k||^2 then gather e_k.
// R2: fp16 split-precision MFMA (virtual K=768: xh*eh + xl*eh + xh*el) for the
// 32768x2048 distance GEMM, top-2 tracking, and an exact-fp32 repair pass for
// rows whose approx gap < DELTA (bitwise-replicates the R1 passing arithmetic).

#define EPSILON 1e-5f
#define DELTA   4e-3f

constexpr int D     = 256;
constexpr int K_TOT = 2048;

typedef _Float16 half8v __attribute__((ext_vector_type(8)));
typedef _Float16 half4v __attribute__((ext_vector_type(4)));
typedef float    f32x4  __attribute__((ext_vector_type(4)));

// ---------------- shared with both paths ----------------
__global__ void esq_kernel(const float* __restrict__ es,
                           const float* __restrict__ usage,
                           float* __restrict__ esq) {
  const int lane = threadIdx.x & 63;
  const int w    = threadIdx.x >> 6;
  const int k    = blockIdx.x * 4 + w;
  const float u  = fmaxf(usage[k], EPSILON);
  const float4 e = *(const float4*)(es + (size_t)k * D + lane * 4);
  const float a = e.x / u, b = e.y / u, c = e.z / u, d = e.w / u;
  float s = a * a + b * b + c * c + d * d;
  #pragma unroll
  for (int m = 1; m < 64; m <<= 1) s += __shfl_xor(s, m, 64);
  if (lane == 0) esq[k] = s;
}

// ---------------- fast path: prep ----------------
__global__ void prep_x_kernel(const float* __restrict__ x,
                              _Float16* __restrict__ xc) {
  const int g = blockIdx.x * 256 + threadIdx.x;
  const int n = g >> 6;
  const int l = g & 63;
  const float4 v = *(const float4*)(x + (size_t)n * D + l * 4);
  half4v h, lo;
  h.x = (_Float16)v.x; lo.x = (_Float16)(v.x - (float)h.x);
  h.y = (_Float16)v.y; lo.y = (_Float16)(v.y - (float)h.y);
  h.z = (_Float16)v.z; lo.z = (_Float16)(v.z - (float)h.z);
  h.w = (_Float16)v.w; lo.w = (_Float16)(v.w - (float)h.w);
  *(half4v*)(xc + (size_t)n * 512 + l * 4)       = h;
  *(half4v*)(xc + (size_t)n * 512 + 256 + l * 4) = lo;
}

__global__ void prep_e_kernel(const float* __restrict__ es,
                              const float* __restrict__ usage,
                              _Float16* __restrict__ ec) {
  const int g = blockIdx.x * 256 + threadIdx.x;
  const int k = g >> 6;
  const int l = g & 63;
  const float u = fmaxf(usage[k], EPSILON);
  const float4 v = *(const float4*)(es + (size_t)k * D + l * 4);
  float4 e;
  e.x = v.x / u; e.y = v.y / u; e.z = v.z / u; e.w = v.w / u;
  half4v h, lo;
  h.x = (_Float16)e.x; lo.x = (_Float16)(e.x - (float)h.x);
  h.y = (_Float16)e.y; lo.y = (_Float16)(e.y - (float)h.y);
  h.z = (_Float16)e.z; lo.z = (_Float16)(e.z - (float)h.z);
  h.w = (_Float16)e.w; lo.w = (_Float16)(e.w - (float)h.w);
  *(half4v*)(ec + (size_t)k * 512 + l * 4)       = h;
  *(half4v*)(ec + (size_t)k * 512 + 256 + l * 4) = lo;
}

__global__ void zero_counter_kernel(int* c) {
  if (threadIdx.x == 0 && blockIdx.x == 0) *c = 0;
}

// ---------------- fast path: MFMA distance GEMM + tile top-2 ----------------
// C-tile 128(n) x 128(k), 4 waves of 64x64, BK=32, virtual K = 768:
// chunks 0-7: xh*eh, 8-15: xl*eh, 16-23: xh*el.
__global__ __launch_bounds__(256)
void mm_kernel(const _Float16* __restrict__ xc, const _Float16* __restrict__ ec,
               const float* __restrict__ esq, float4* __restrict__ p4, int N) {
  __shared__ __align__(16) _Float16 sA[128 * 32];
  __shared__ __align__(16) _Float16 sB[128 * 32];
  const int t    = threadIdx.x;
  const int lane = t & 63;
  const int wid  = t >> 6;
  const int wn   = wid >> 1;
  const int wk   = wid & 1;
  const int n0   = blockIdx.y * 128;
  const int k0   = blockIdx.x * 128;

  f32x4 acc[4][4] = {};

  for (int ka = 0; ka < 24; ++ka) {
    const int acol = (ka < 16) ? ka : ka - 16;  // xh | xl | xh
    const int bcol = (ka < 8)  ? ka : ka - 8;   // eh | eh | el
    __syncthreads();
    #pragma unroll
    for (int i = 0; i < 2; ++i) {
      const int p   = i * 256 + t;       // 16B piece id 0..511
      const int row = p >> 2;
      const int c   = p & 3;
      const _Float16* ga = xc + (size_t)(n0 + row) * 512 + acol * 32 + c * 8;
      __builtin_amdgcn_global_load_lds(
          (const __attribute__((address_space(1))) void*)ga,
          (__attribute__((address_space(3))) void*)&sA[p * 8], 16, 0, 0);
      const _Float16* gb = ec + (size_t)(k0 + row) * 512 + bcol * 32 + c * 8;
      __builtin_amdgcn_global_load_lds(
          (const __attribute__((address_space(1))) void*)gb,
          (__attribute__((address_space(3))) void*)&sB[p * 8], 16, 0, 0);
    }
    __syncthreads();

    half8v af[4], bf[4];
    #pragma unroll
    for (int mi = 0; mi < 4; ++mi)
      af[mi] = *(const half8v*)&sA[(wn * 64 + mi * 16 + (lane & 15)) * 32 +
                                   (lane >> 4) * 8];
    #pragma unroll
    for (int ni = 0; ni < 4; ++ni)
      bf[ni] = *(const half8v*)&sB[(wk * 64 + ni * 16 + (lane & 15)) * 32 +
                                   (lane >> 4) * 8];
    #pragma unroll
    for (int mi = 0; mi < 4; ++mi)
      #pragma unroll
      for (int ni = 0; ni < 4; ++ni)
        acc[mi][ni] = __builtin_amdgcn_mfma_f32_16x16x32_f16(
            af[mi], bf[ni], acc[mi][ni], 0, 0, 0);
  }

  // Epilogue: dist = esq - 2*dot; per-row (n) top-2 over this wave's 64 k cols.
  // C layout: col = lane&15 (k), row = (lane>>4)*4 + r (n).
  float eqv[4];
  int   kc[4];
  #pragma unroll
  for (int ni = 0; ni < 4; ++ni) {
    kc[ni]  = k0 + wk * 64 + ni * 16 + (lane & 15);
    eqv[ni] = esq[kc[ni]];
  }
  const int pt = blockIdx.x * 2 + wk;  // partial column 0..31
  #pragma unroll
  for (int mi = 0; mi < 4; ++mi) {
    #pragma unroll
    for (int r = 0; r < 4; ++r) {
      float d0 = FLT_MAX, d1 = FLT_MAX;
      int   i0 = 0x7fffffff;
      #pragma unroll
      for (int ni = 0; ni < 4; ++ni) {
        const float d = fmaf(-2.f, acc[mi][ni][r], eqv[ni]);
        if (d < d0) { d1 = d0; d0 = d; i0 = kc[ni]; }
        else if (d < d1) { d1 = d; }
      }
      #pragma unroll
      for (int off = 1; off < 16; off <<= 1) {
        const float od0 = __shfl_xor(d0, off, 16);
        const int   oi0 = __shfl_xor(i0, off, 16);
        const float od1 = __shfl_xor(d1, off, 16);
        if (od0 < d0 || (od0 == d0 && oi0 < i0)) {
          d1 = fminf(d0, od1); d0 = od0; i0 = oi0;
        } else {
          d1 = fminf(d1, od0);
        }
      }
      if ((lane & 15) == mi * 4 + r) {
        const int n = n0 + wn * 64 + mi * 16 + (lane >> 4) * 4 + r;
        p4[(size_t)n * 32 + pt] =
            make_float4(d0, __int_as_float(i0), d1, 0.f);
      }
    }
  }
}

// ---------------- fast path: combine partials + gather + flag ----------------
__global__ void combine_kernel(const float4* __restrict__ p4,
                               const float* __restrict__ es,
                               const float* __restrict__ usage,
                               float* __restrict__ out_q,
                               float* __restrict__ out_i,
                               int* __restrict__ list,
                               int* __restrict__ counter, int N) {
  const int wid  = threadIdx.x >> 6;
  const int lane = threadIdx.x & 63;
  const int n    = blockIdx.x * 4 + wid;

  float d0 = FLT_MAX, d1 = FLT_MAX;
  int   i0 = 0x7fffffff;
  if (lane < 32) {
    const float4 pv = p4[(size_t)n * 32 + lane];
    d0 = pv.x; i0 = __float_as_int(pv.y); d1 = pv.z;
  }
  #pragma unroll
  for (int off = 1; off < 64; off <<= 1) {
    const float od0 = __shfl_xor(d0, off, 64);
    const int   oi0 = __shfl_xor(i0, off, 64);
    const float od1 = __shfl_xor(d1, off, 64);
    if (od0 < d0 || (od0 == d0 && oi0 < i0)) {
      d1 = fminf(d0, od1); d0 = od0; i0 = oi0;
    } else {
      d1 = fminf(d1, od0);
    }
  }
  const int idx = i0;
  const float u = fmaxf(usage[idx], EPSILON);
  const float4 e = *(const float4*)(es + (size_t)idx * D + lane * 4);
  float4 q;
  q.x = e.x / u; q.y = e.y / u; q.z = e.z / u; q.w = e.w / u;
  *(float4*)(out_q + (size_t)n * D + lane * 4) = q;
  if (lane == 0) {
    out_i[n] = (float)idx;
    if (d1 - d0 < DELTA) {
      const int pos = atomicAdd(counter, 1);
      list[pos] = n;
    }
  }
}

// ---------------- fast path: exact fp32 repair for flagged rows ----------------
__global__ void repair_kernel(const float* __restrict__ x,
                              const float* __restrict__ es,
                              const float* __restrict__ usage,
                              const float* __restrict__ esq,
                              const int* __restrict__ list,
                              const int* __restrict__ counter,
                              float* __restrict__ out_q,
                              float* __restrict__ out_i, int N) {
  __shared__ float xs[256];
  __shared__ float swd[4];
  __shared__ int   swi[4];
  __shared__ int   sbi;
  const int t    = threadIdx.x;
  const int w    = t >> 6;
  const int lane = t & 63;
  const int cnt  = *counter;

  for (int j = blockIdx.x; j < cnt; j += 1024) {
    const int n = list[j];
    __syncthreads();
    xs[t] = x[(size_t)n * D + t];
    __syncthreads();
    const float4 xv = *(const float4*)&xs[lane * 4];

    float bd = FLT_MAX;
    int   bi = 0x7fffffff;
    for (int kk = 0; kk < K_TOT / 4; ++kk) {
      const int k = w * (K_TOT / 4) + kk;   // ascending per wave
      const float rs = 1.0f / fmaxf(usage[k], EPSILON);
      const float4 e = *(const float4*)(es + (size_t)k * D + lane * 4);
      float pd = xv.x * (e.x * rs);
      pd = fmaf(xv.y, e.y * rs, pd);
      pd = fmaf(xv.z, e.z * rs, pd);
      pd = fmaf(xv.w, e.w * rs, pd);
      #pragma unroll
      for (int off = 1; off < 64; off <<= 1) pd += __shfl_xor(pd, off, 64);
      const float dst = fmaf(-2.f, pd, esq[k]);
      if (dst < bd) { bd = dst; bi = k; }
    }
    if (lane == 0) { swd[w] = bd; swi[w] = bi; }
    __syncthreads();
    if (t == 0) {
      float gd = swd[0]; int gi = swi[0];
      #pragma unroll
      for (int q = 1; q < 4; ++q) {
        if (swd[q] < gd || (swd[q] == gd && swi[q] < gi)) {
          gd = swd[q]; gi = swi[q];
        }
      }
      sbi = gi;
    }
    __syncthreads();
    const int idx = sbi;
    const float u = fmaxf(usage[idx], EPSILON);
    out_q[(size_t)n * D + t] = es[(size_t)idx * D + t] / u;
    if (t == 0) out_i[n] = (float)idx;
  }
}

// ---------------- fallback path (R1, fp32 vector) ----------------
constexpr int TN = 128;
constexpr int TK = 128;
constexpr int DC = 32;
constexpr int KS = 2;
constexpr int RS = 196;

__global__ __launch_bounds__(256, 2)
void dist_kernel(const float* __restrict__ x,
                 const float* __restrict__ es,
                 const float* __restrict__ usage,
                 const float* __restrict__ esq,
                 float* __restrict__ bestd,
                 int* __restrict__ besti, int N) {
  __shared__ float smX[DC * RS];
  __shared__ float smE[DC * RS];
  const int t    = threadIdx.x;
  const int tx   = t & 15;
  const int ty   = t >> 4;
  const int n0   = blockIdx.x * TN;
  const int half = blockIdx.y;

  float best[8];
  int   bidx[8];
  #pragma unroll
  for (int i = 0; i < 8; ++i) { best[i] = FLT_MAX; bidx[i] = 0; }

  for (int kt = 0; kt < (K_TOT / KS) / TK; ++kt) {
    const int k0 = half * (K_TOT / KS) + kt * TK;
    float acc[8][8];
    #pragma unroll
    for (int i = 0; i < 8; ++i)
      #pragma unroll
      for (int j = 0; j < 8; ++j) acc[i][j] = 0.f;

    for (int dc = 0; dc < D; dc += DC) {
      __syncthreads();
      #pragma unroll
      for (int i = 0; i < 4; ++i) {
        const int f    = i * 256 + t;
        const int row  = f >> 3;
        const int c4   = f & 7;
        const int pcol = row + ((row >> 3) << 2);
        const float4 xv =
            *(const float4*)(x + (size_t)(n0 + row) * D + dc + c4 * 4);
        smX[(c4 * 4 + 0) * RS + pcol] = xv.x;
        smX[(c4 * 4 + 1) * RS + pcol] = xv.y;
        smX[(c4 * 4 + 2) * RS + pcol] = xv.z;
        smX[(c4 * 4 + 3) * RS + pcol] = xv.w;
        const int kk = k0 + row;
        const float rs = 1.0f / fmaxf(usage[kk], EPSILON);
        const float4 ev =
            *(const float4*)(es + (size_t)kk * D + dc + c4 * 4);
        smE[(c4 * 4 + 0) * RS + pcol] = ev.x * rs;
        smE[(c4 * 4 + 1) * RS + pcol] = ev.y * rs;
        smE[(c4 * 4 + 2) * RS + pcol] = ev.z * rs;
        smE[(c4 * 4 + 3) * RS + pcol] = ev.w * rs;
      }
      __syncthreads();
      #pragma unroll 4
      for (int d = 0; d < DC; ++d) {
        const float* px = &smX[d * RS + ty * 12];
        const float* pe = &smE[d * RS + tx * 12];
        const float4 xa = *(const float4*)px;
        const float4 xb = *(const float4*)(px + 4);
        const float4 ea = *(const float4*)pe;
        const float4 eb = *(const float4*)(pe + 4);
        const float xr[8] = {xa.x, xa.y, xa.z, xa.w, xb.x, xb.y, xb.z, xb.w};
        const float er[8] = {ea.x, ea.y, ea.z, ea.w, eb.x, eb.y, eb.z, eb.w};
        #pragma unroll
        for (int i = 0; i < 8; ++i)
          #pragma unroll
          for (int jj = 0; jj < 8; ++jj)
            acc[i][jj] = fmaf(xr[i], er[jj], acc[i][jj]);
      }
    }
    #pragma unroll
    for (int jj = 0; jj < 8; ++jj) {
      const int k = k0 + tx * 8 + jj;
      const float eq = esq[k];
      #pragma unroll
      for (int i = 0; i < 8; ++i) {
        const float dst = fmaf(-2.0f, acc[i][jj], eq);
        if (dst < best[i]) { best[i] = dst; bidx[i] = k; }
      }
    }
  }
  __syncthreads();
  float* rd = smX;
  int*   ri = (int*)smE;
  #pragma unroll
  for (int i = 0; i < 8; ++i) {
    const int r = ty * 8 + i;
    rd[tx * TN + r] = best[i];
    ri[tx * TN + r] = bidx[i];
  }
  __syncthreads();
  for (int off = 8; off >= 1; off >>= 1) {
    if (tx < off) {
      #pragma unroll
      for (int i = 0; i < 8; ++i) {
        const int r = ty * 8 + i;
        const float da = rd[tx * TN + r], db = rd[(tx + off) * TN + r];
        const int   ia = ri[tx * TN + r], ib = ri[(tx + off) * TN + r];
        if (db < da || (db == da && ib < ia)) {
          rd[tx * TN + r] = db;
          ri[tx * TN + r] = ib;
        }
      }
    }
    __syncthreads();
  }
  if (tx == 0) {
    #pragma unroll
    for (int i = 0; i < 8; ++i) {
      const int r = ty * 8 + i;
      bestd[(size_t)half * N + n0 + r] = rd[r];
      besti[(size_t)half * N + n0 + r] = ri[r];
    }
  }
}

__global__ void gather_kernel(const float* __restrict__ es,
                              const float* __restrict__ usage,
                              const float* __restrict__ bestd,
                              const int* __restrict__ besti,
                              float* __restrict__ out_q,
                              float* __restrict__ out_i, int N) {
  const int w    = threadIdx.x >> 6;
  const int lane = threadIdx.x & 63;
  const int n    = blockIdx.x * 4 + w;
  const float d0 = bestd[n];
  const float d1 = bestd[(size_t)N + n];
  const int   i0 = besti[n];
  const int   i1 = besti[(size_t)N + n];
  const int idx = (d1 < d0) ? i1 : i0;
  const float u = fmaxf(usage[idx], EPSILON);
  const float4 e = *(const float4*)(es + (size_t)idx * D + lane * 4);
  float4 q;
  q.x = e.x / u; q.y = e.y / u; q.z = e.z / u; q.w = e.w / u;
  *(float4*)(out_q + (size_t)n * D + lane * 4) = q;
  if (lane == 0) out_i[n] = (float)idx;
}

// ---------------- launch ----------------
extern "C" void kernel_launch(void* const* d_in, const int* in_sizes, int n_in,
                              void* d_out, int out_size, void* d_ws, size_t ws_size,
                              hipStream_t stream) {
  const float* x     = (const float*)d_in[0];  // [N, 256]
  const float* es    = (const float*)d_in[1];  // [2048, 256]
  const float* usage = (const float*)d_in[2];  // [2048]
  const int N = in_sizes[0] / D;               // 32768

  float* out_q = (float*)d_out;
  float* out_i = out_q + (size_t)N * D;

  // fast-path workspace carve-up
  const size_t XB = (size_t)N * 512 * 2;        // 33,554,432
  const size_t EB = (size_t)K_TOT * 512 * 2;    //  2,097,152
  const size_t PB = (size_t)N * 32 * 16;        // 16,777,216
  const size_t off_ec   = XB;
  const size_t off_p4   = XB + EB;
  const size_t off_esq  = off_p4 + PB;
  const size_t off_list = off_esq + 8192;
  const size_t off_cnt  = off_list + (size_t)N * 4;
  const size_t NEED     = off_cnt + 16;

  char* wsb = (char*)d_ws;

  if (ws_size >= NEED) {
    _Float16* xc   = (_Float16*)wsb;
    _Float16* ec   = (_Float16*)(wsb + off_ec);
    float4*   p4   = (float4*)(wsb + off_p4);
    float*    esq  = (float*)(wsb + off_esq);
    int*      list = (int*)(wsb + off_list);
    int*      cnt  = (int*)(wsb + off_cnt);

    zero_counter_kernel<<<1, 64, 0, stream>>>(cnt);
    esq_kernel<<<K_TOT / 4, 256, 0, stream>>>(es, usage, esq);
    prep_x_kernel<<<N * 64 / 256, 256, 0, stream>>>(x, xc);
    prep_e_kernel<<<K_TOT * 64 / 256, 256, 0, stream>>>(es, usage, ec);
    mm_kernel<<<dim3(K_TOT / 128, N / 128), 256, 0, stream>>>(xc, ec, esq, p4, N);
    combine_kernel<<<N / 4, 256, 0, stream>>>(p4, es, usage, out_q, out_i,
                                              list, cnt, N);
    repair_kernel<<<1024, 256, 0, stream>>>(x, es, usage, esq, list, cnt,
                                            out_q, out_i, N);
  } else {
    float* ws    = (float*)d_ws;
    float* esq   = ws;
    float* bestd = ws + K_TOT;
    int*   besti = (int*)(ws + K_TOT + (size_t)KS * N);
    esq_kernel<<<K_TOT / 4, 256, 0, stream>>>(es, usage, esq);
    dist_kernel<<<dim3(N / TN, KS), 256, 0, stream>>>(x, es, usage, esq,
                                                      bestd, besti, N);
    gather_kernel<<<N / 4, 256, 0, stream>>>(es, usage, bestd, besti,
                                             out_q, out_i, N);
  }
}